// Round 6
// baseline (190.368 us; speedup 1.0000x reference)
//
#include <hip/hip_runtime.h>
#include <hip/hip_bf16.h>

typedef __attribute__((ext_vector_type(8))) short s16x8;
typedef __attribute__((ext_vector_type(4))) float f32x4;

#define K_DIM 1024
#define I_DIM 4096
#define BK2 32
#define NT2 (K_DIM / BK2)  // 32 K-tiles
// block tile 128 (M) x 256 (N); 4 waves, each 128x64

__device__ __forceinline__ unsigned short f2bf_bits(float v) {
    // exact for integers |v| <= 255
    return (unsigned short)(__builtin_bit_cast(unsigned int, v) >> 16);
}

__device__ __forceinline__ float fakeq_int(float x, float s, float zp) {
    float q = fminf(fmaxf(rintf(x / s) + zp, 0.0f), 255.0f);
    return q - zp;
}

// branch-free tanh-GELU: |err vs exact| <= ~3e-4
__device__ __forceinline__ float gelu_tanh(float y) {
    float y2 = y * y;
    float z = y * fmaf(0.0356774081f, y2, 0.7978845608f);
    return y / (1.0f + __expf(-2.0f * z));
}

// ---- quantize activations: fp32 [M*K] -> bf16 integer codes (q - zp)
__global__ void quant_x_kernel(const float* __restrict__ x, unsigned short* __restrict__ Aq,
                               const float* __restrict__ a_scale, const float* __restrict__ a_zero,
                               long long n) {
    long long i = ((long long)blockIdx.x * blockDim.x + threadIdx.x) * 4;
    if (i >= n) return;
    float s = a_scale[0];
    float zp = rintf(a_zero[0]);
    float4 v = *(const float4*)(x + i);
    ushort4 o;
    o.x = f2bf_bits(fakeq_int(v.x, s, zp));
    o.y = f2bf_bits(fakeq_int(v.y, s, zp));
    o.z = f2bf_bits(fakeq_int(v.z, s, zp));
    o.w = f2bf_bits(fakeq_int(v.w, s, zp));
    *(ushort4*)(Aq + i) = o;
}

// ---- quantize weights: per-row scale/zero
__global__ void quant_w_kernel(const float* __restrict__ w, unsigned short* __restrict__ Wq,
                               const float* __restrict__ w_scale, const float* __restrict__ w_zero,
                               long long n) {
    long long i = ((long long)blockIdx.x * blockDim.x + threadIdx.x) * 4;
    if (i >= n) return;
    long long row = i >> 10;  // K = 1024
    float s = w_scale[row];
    float zp = rintf(w_zero[row]);
    float4 v = *(const float4*)(w + i);
    ushort4 o;
    o.x = f2bf_bits(fakeq_int(v.x, s, zp));
    o.y = f2bf_bits(fakeq_int(v.y, s, zp));
    o.z = f2bf_bits(fakeq_int(v.z, s, zp));
    o.w = f2bf_bits(fakeq_int(v.w, s, zp));
    *(ushort4*)(Wq + i) = o;
}

#define GLL(SRC, DST)                                                         \
    __builtin_amdgcn_global_load_lds(                                         \
        (const __attribute__((address_space(1))) void*)(SRC),                 \
        (__attribute__((address_space(3))) void*)(DST), 16, 0, 0)

// stage K-tile TT (A 128x32 = 2 chunks, B 256x32 = 4 chunks) into buffer BUF
#define STAGE(TT, BUF)                                            \
    do {                                                          \
        GLL(pA0 + (TT) * BK2, As + (BUF) * 4096 + dA);            \
        GLL(pA1 + (TT) * BK2, As + (BUF) * 4096 + 2048 + dA);     \
        GLL(pB0 + (TT) * BK2, Bs + (BUF) * 8192 + dA);            \
        GLL(pB1 + (TT) * BK2, Bs + (BUF) * 8192 + 2048 + dA);     \
        GLL(pB2 + (TT) * BK2, Bs + (BUF) * 8192 + 4096 + dA);     \
        GLL(pB3 + (TT) * BK2, Bs + (BUF) * 8192 + 6144 + dA);     \
    } while (0)

// ---- 128x256x32 GEMM, per-wave 128x64, triple-buffered LDS (72KB, 2 blocks/CU),
//      rotation slot-swizzle (conflict-free), counted vmcnt, fused epilogue.
__global__ __launch_bounds__(256, 2) void gemm_gelu_kernel(
    const unsigned short* __restrict__ Aq,   // [M][K] bf16 integer codes
    const unsigned short* __restrict__ Wq,   // [I][K]
    const float* __restrict__ bias,
    const float* __restrict__ w_scale,
    const float* __restrict__ a_scale,
    float* __restrict__ out,                 // [M][I] fp32
    int M, int Ntiles) {
    __shared__ alignas(16) unsigned short As[3 * 128 * BK2];  // 24 KB
    __shared__ alignas(16) unsigned short Bs[3 * 256 * BK2];  // 48 KB

    // bijective XCD-aware swizzle (nwg % 8 == 0)
    int nwg = gridDim.x, bid = blockIdx.x;
    int xcd = bid & 7, lin = bid >> 3;
    int q8 = nwg >> 3, r8 = nwg & 7;
    int swz = (xcd < r8 ? xcd * (q8 + 1) : r8 * (q8 + 1) + (xcd - r8) * q8) + lin;
    int mt = swz / Ntiles, nt = swz % Ntiles;

    int tid = threadIdx.x;
    int wave = tid >> 6, lane = tid & 63;

    long long mrow0 = (long long)mt * 128;
    int ncol0 = nt * 256;

    // staging: thread t covers row (chunk*64 + t>>2), LDS slot j = t&3.
    // rotation swizzle: LDS[row][j] holds source slot (j - (row>>1)) & 3
    int r0 = tid >> 2;                                  // 0..63
    int slotsrc = ((tid & 3) - ((tid >> 3) & 3)) & 3;   // (j - (row>>1)) & 3
    long long mmax = (long long)M - 1;
    long long raA0 = mrow0 + r0;        if (raA0 > mmax) raA0 = mmax;
    long long raA1 = mrow0 + 64 + r0;   if (raA1 > mmax) raA1 = mmax;
    const unsigned short* pA0 = Aq + raA0 * K_DIM + slotsrc * 8;
    const unsigned short* pA1 = Aq + raA1 * K_DIM + slotsrc * 8;
    const unsigned short* pB0 = Wq + ((long long)ncol0 + r0) * K_DIM + slotsrc * 8;
    const unsigned short* pB1 = Wq + ((long long)ncol0 + 64 + r0) * K_DIM + slotsrc * 8;
    const unsigned short* pB2 = Wq + ((long long)ncol0 + 128 + r0) * K_DIM + slotsrc * 8;
    const unsigned short* pB3 = Wq + ((long long)ncol0 + 192 + r0) * K_DIM + slotsrc * 8;
    int dA = tid * 8;  // linear dest within region (elements)

    // ds_read: lane (r = lane&15, q = lane>>4) reads LDS slot (q + (r>>1)) & 3
    int koffe = (((lane >> 4) + ((lane >> 1) & 3)) & 3) * 8;
    int arowb = lane & 15;               // A frags: rows mi*16 + arowb (mi 0..7)
    int browb = wave * 64 + (lane & 15); // B frags: cols n*16 + browb (n 0..3)

    f32x4 acc[8][4];
#pragma unroll
    for (int m = 0; m < 8; ++m)
#pragma unroll
        for (int n = 0; n < 4; ++n) acc[m][n] = (f32x4)0.0f;

    // prologue: stage tiles 0 and 1; wait tile 0 (tile 1's 6 stay in flight)
    STAGE(0, 0);
    STAGE(1, 1);
    asm volatile("s_waitcnt vmcnt(6)" ::: "memory");
    __builtin_amdgcn_s_barrier();

    int buf = 0, bs2 = 2;
    for (int t = 0; t < NT2; ++t) {
        if (t + 2 < NT2) STAGE(t + 2, bs2);  // 2-tile lead

        s16x8 a[8], b[4];
#pragma unroll
        for (int mi = 0; mi < 8; ++mi)
            a[mi] = *(const s16x8*)(As + buf * 4096 + (arowb + mi * 16) * BK2 + koffe);
#pragma unroll
        for (int n = 0; n < 4; ++n)
            b[n] = *(const s16x8*)(Bs + buf * 8192 + (browb + n * 16) * BK2 + koffe);

        __builtin_amdgcn_s_setprio(1);
#pragma unroll
        for (int mi = 0; mi < 8; ++mi)
#pragma unroll
            for (int n = 0; n < 4; ++n)
                acc[mi][n] = __builtin_amdgcn_mfma_f32_16x16x32_bf16(a[mi], b[n], acc[mi][n], 0, 0, 0);
        __builtin_amdgcn_s_setprio(0);

        // ensure tile t+1 landed; keep tile t+2's 6 loads in flight
        if (t + 2 < NT2) {
            asm volatile("s_waitcnt vmcnt(6)" ::: "memory");
        } else if (t + 1 < NT2) {
            asm volatile("s_waitcnt vmcnt(0)" ::: "memory");
        }
        if (t + 1 < NT2) __builtin_amdgcn_s_barrier();

        buf = (buf == 2) ? 0 : buf + 1;
        bs2 = (bs2 == 2) ? 0 : bs2 + 1;
    }

    // epilogue: y = a_scale*w_scale[col]*acc + bias[col]; tanh-GELU
    float asc = a_scale[0];
    int colb = ncol0 + wave * 64 + (lane & 15);
    int rsubE = (lane >> 4) * 4;
    bool fullTile = (mrow0 + 128 <= (long long)M);
    if (fullTile) {
#pragma unroll
        for (int n = 0; n < 4; ++n) {
            int col = colb + n * 16;
            float sc = asc * w_scale[col];
            float bz = bias[col];
#pragma unroll
            for (int m = 0; m < 8; ++m) {
                long long rb = mrow0 + m * 16 + rsubE;
#pragma unroll
                for (int rg = 0; rg < 4; ++rg) {
                    float y = acc[m][n][rg] * sc + bz;
                    out[(rb + rg) * I_DIM + col] = gelu_tanh(y);
                }
            }
        }
    } else {
#pragma unroll
        for (int n = 0; n < 4; ++n) {
            int col = colb + n * 16;
            float sc = asc * w_scale[col];
            float bz = bias[col];
#pragma unroll
            for (int m = 0; m < 8; ++m) {
                long long rb = mrow0 + m * 16 + rsubE;
#pragma unroll
                for (int rg = 0; rg < 4; ++rg) {
                    long long rowi = rb + rg;
                    if (rowi < M) {
                        float y = acc[m][n][rg] * sc + bz;
                        out[rowi * I_DIM + col] = gelu_tanh(y);
                    }
                }
            }
        }
    }
}

// ---- safety-net fallback (workspace too small): naive on-the-fly
__global__ void fallback_kernel(const float* __restrict__ x, const float* __restrict__ w,
                                const float* __restrict__ bias, const float* __restrict__ w_scale,
                                const float* __restrict__ w_zero, const float* __restrict__ a_scale,
                                const float* __restrict__ a_zero, float* __restrict__ out,
                                long long M) {
    long long gid = (long long)blockIdx.x * blockDim.x + threadIdx.x;
    if (gid >= M * I_DIM) return;
    int i = (int)(gid & (I_DIM - 1));
    long long row = gid >> 12;
    float as = a_scale[0], az = rintf(a_zero[0]);
    float wsc = w_scale[i], wz = rintf(w_zero[i]);
    const float* xr = x + row * K_DIM;
    const float* wrp = w + (long long)i * K_DIM;
    float accf = 0.0f;
    for (int k = 0; k < K_DIM; ++k)
        accf += fakeq_int(xr[k], as, az) * fakeq_int(wrp[k], wsc, wz);
    float y = accf * as * wsc + bias[i];
    out[gid] = 0.5f * y * (1.0f + erff(y * 0.70710678118654752f));
}

extern "C" void kernel_launch(void* const* d_in, const int* in_sizes, int n_in,
                              void* d_out, int out_size, void* d_ws, size_t ws_size,
                              hipStream_t stream) {
    const float* x       = (const float*)d_in[0];
    const float* w       = (const float*)d_in[1];
    const float* bias    = (const float*)d_in[2];
    const float* w_scale = (const float*)d_in[3];
    const float* w_zero  = (const float*)d_in[4];
    const float* a_scale = (const float*)d_in[5];
    const float* a_zero  = (const float*)d_in[6];
    float* out = (float*)d_out;

    long long n_x = in_sizes[0];  // M*K
    long long M = n_x / K_DIM;    // 12608
    size_t needA = (size_t)n_x * 2;
    size_t needW = (size_t)I_DIM * K_DIM * 2;

    if (ws_size >= needA + needW) {
        unsigned short* Aq = (unsigned short*)d_ws;
        unsigned short* Wq = (unsigned short*)((char*)d_ws + needA);

        long long blocksX = (n_x / 4 + 255) / 256;
        quant_x_kernel<<<(int)blocksX, 256, 0, stream>>>(x, Aq, a_scale, a_zero, n_x);

        long long ndw = (long long)I_DIM * K_DIM;
        long long blocksW = (ndw / 4 + 255) / 256;
        quant_w_kernel<<<(int)blocksW, 256, 0, stream>>>(w, Wq, w_scale, w_zero, ndw);

        int Mtiles = (int)((M + 127) / 128);  // 99
        int Ntiles = I_DIM / 256;             // 16
        gemm_gelu_kernel<<<Mtiles * Ntiles, 256, 0, stream>>>(Aq, Wq, bias, w_scale, a_scale,
                                                              out, (int)M, Ntiles);
    } else {
        long long total = M * I_DIM;
        long long blocks = (total + 255) / 256;
        fallback_kernel<<<(int)blocks, 256, 0, stream>>>(x, w, bias, w_scale, w_zero,
                                                         a_scale, a_zero, out, M);
    }
}

// Round 7
// 130.652 us; speedup vs baseline: 1.4571x; 1.4571x over previous
//
#include <hip/hip_runtime.h>
#include <hip/hip_bf16.h>

typedef __attribute__((ext_vector_type(4))) int i32x4;
typedef __attribute__((ext_vector_type(4))) float f32x4;

#define K_DIM 1024
#define I_DIM 4096
#define BK3 64
#define NT3 (K_DIM / BK3)  // 16 K-tiles
// block tile 128x128, 4 waves (2x2), per-wave 64x64, i8 MFMA 16x16x64

__device__ __forceinline__ float fakeq_int(float x, float s, float zp) {
    // round(x/s)+zp clipped to [0,255], minus zp -> exact integer in [-128,127]
    float q = fminf(fmaxf(rintf(x / s) + zp, 0.0f), 255.0f);
    return q - zp;
}

// branch-free tanh-GELU: |err vs exact| <= ~3e-4
__device__ __forceinline__ float gelu_tanh(float y) {
    float y2 = y * y;
    float z = y * fmaf(0.0356774081f, y2, 0.7978845608f);
    return y / (1.0f + __expf(-2.0f * z));
}

// ---- quantize activations: fp32 -> int8 codes (q - zp), 8 elems/thread
__global__ void quant_x_kernel(const float* __restrict__ x, signed char* __restrict__ Aq,
                               const float* __restrict__ a_scale, const float* __restrict__ a_zero,
                               long long n) {
    long long i = ((long long)blockIdx.x * blockDim.x + threadIdx.x) * 8;
    if (i >= n) return;
    float s = a_scale[0];
    float zp = rintf(a_zero[0]);
    float4 v0 = *(const float4*)(x + i);
    float4 v1 = *(const float4*)(x + i + 4);
    int q0 = (int)fakeq_int(v0.x, s, zp), q1 = (int)fakeq_int(v0.y, s, zp);
    int q2 = (int)fakeq_int(v0.z, s, zp), q3 = (int)fakeq_int(v0.w, s, zp);
    int q4 = (int)fakeq_int(v1.x, s, zp), q5 = (int)fakeq_int(v1.y, s, zp);
    int q6 = (int)fakeq_int(v1.z, s, zp), q7 = (int)fakeq_int(v1.w, s, zp);
    int lo = (q0 & 255) | ((q1 & 255) << 8) | ((q2 & 255) << 16) | ((q3 & 255) << 24);
    int hi = (q4 & 255) | ((q5 & 255) << 8) | ((q6 & 255) << 16) | ((q7 & 255) << 24);
    *(int2*)(Aq + i) = make_int2(lo, hi);
}

// ---- quantize weights: per-row scale/zero, 8 elems/thread
__global__ void quant_w_kernel(const float* __restrict__ w, signed char* __restrict__ Wq,
                               const float* __restrict__ w_scale, const float* __restrict__ w_zero,
                               long long n) {
    long long i = ((long long)blockIdx.x * blockDim.x + threadIdx.x) * 8;
    if (i >= n) return;
    long long row = i >> 10;  // K = 1024
    float s = w_scale[row];
    float zp = rintf(w_zero[row]);
    float4 v0 = *(const float4*)(w + i);
    float4 v1 = *(const float4*)(w + i + 4);
    int q0 = (int)fakeq_int(v0.x, s, zp), q1 = (int)fakeq_int(v0.y, s, zp);
    int q2 = (int)fakeq_int(v0.z, s, zp), q3 = (int)fakeq_int(v0.w, s, zp);
    int q4 = (int)fakeq_int(v1.x, s, zp), q5 = (int)fakeq_int(v1.y, s, zp);
    int q6 = (int)fakeq_int(v1.z, s, zp), q7 = (int)fakeq_int(v1.w, s, zp);
    int lo = (q0 & 255) | ((q1 & 255) << 8) | ((q2 & 255) << 16) | ((q3 & 255) << 24);
    int hi = (q4 & 255) | ((q5 & 255) << 8) | ((q6 & 255) << 16) | ((q7 & 255) << 24);
    *(int2*)(Wq + i) = make_int2(lo, hi);
}

#define GLL(SRC, DST)                                                         \
    __builtin_amdgcn_global_load_lds(                                         \
        (const __attribute__((address_space(1))) void*)(SRC),                 \
        (__attribute__((address_space(3))) void*)(DST), 16, 0, 0)

// stage K-tile TT (A 128x64B + B 128x64B) into buffer BUF: 4 GLL/thread
#define STAGE(TT, BUF)                                          \
    do {                                                        \
        GLL(pA0 + (TT) * BK3, As + (BUF) * 8192 + dA);          \
        GLL(pA1 + (TT) * BK3, As + (BUF) * 8192 + 4096 + dA);   \
        GLL(pB0 + (TT) * BK3, Bs + (BUF) * 8192 + dA);          \
        GLL(pB1 + (TT) * BK3, Bs + (BUF) * 8192 + 4096 + dA);   \
    } while (0)

// ---- 128x128x64 i8 GEMM, triple-buffered LDS (48KB -> 3 blocks/CU),
//      rotation slot-swizzle (conflict-free, HW-verified r6), counted vmcnt.
__global__ __launch_bounds__(256, 3) void gemm_gelu_kernel(
    const signed char* __restrict__ Aq,   // [M][K] int8 codes
    const signed char* __restrict__ Wq,   // [I][K]
    const float* __restrict__ bias,
    const float* __restrict__ w_scale,
    const float* __restrict__ a_scale,
    float* __restrict__ out,              // [M][I] fp32
    int M, int Ntiles) {
    __shared__ alignas(16) signed char As[3 * 128 * BK3];  // 24 KB
    __shared__ alignas(16) signed char Bs[3 * 128 * BK3];  // 24 KB

    // bijective XCD-aware swizzle (nwg % 8 == 0)
    int nwg = gridDim.x, bid = blockIdx.x;
    int xcd = bid & 7, lin = bid >> 3;
    int q8 = nwg >> 3, r8 = nwg & 7;
    int swz = (xcd < r8 ? xcd * (q8 + 1) : r8 * (q8 + 1) + (xcd - r8) * q8) + lin;
    int mt = swz / Ntiles, nt = swz % Ntiles;

    int tid = threadIdx.x;
    int wave = tid >> 6, lane = tid & 63;
    int wr = wave >> 1, wc = wave & 1;  // 2x2 waves, per-wave 64x64

    long long mrow0 = (long long)mt * 128;
    int ncol0 = nt * 128;

    // staging: thread t covers row (chunk*64 + t>>2), LDS slot j = t&3 (16B slots).
    // rotation swizzle: LDS[row][j] holds source slot (j - (row>>1)) & 3
    int r0 = tid >> 2;                                  // 0..63
    int slotsrc = ((tid & 3) - ((tid >> 3) & 3)) & 3;
    long long mmax = (long long)M - 1;
    long long raA0 = mrow0 + r0;        if (raA0 > mmax) raA0 = mmax;
    long long raA1 = mrow0 + 64 + r0;   if (raA1 > mmax) raA1 = mmax;
    const signed char* pA0 = Aq + raA0 * K_DIM + slotsrc * 16;
    const signed char* pA1 = Aq + raA1 * K_DIM + slotsrc * 16;
    const signed char* pB0 = Wq + ((long long)ncol0 + r0) * K_DIM + slotsrc * 16;
    const signed char* pB1 = Wq + ((long long)ncol0 + 64 + r0) * K_DIM + slotsrc * 16;
    int dA = tid * 16;  // linear byte dest within 4KB region

    // ds_read: lane (r = lane&15, q = lane>>4) reads slot (q + (r>>1)) & 3
    int koffb = (((lane >> 4) + ((lane >> 1) & 3)) & 3) * 16;
    int arowb = wr * 64 + (lane & 15);
    int browb = wc * 64 + (lane & 15);

    i32x4 acc[4][4];
#pragma unroll
    for (int m = 0; m < 4; ++m)
#pragma unroll
        for (int n = 0; n < 4; ++n) acc[m][n] = (i32x4)0;

    // prologue: stage tiles 0,1; wait tile 0 (tile 1's 4 stay in flight)
    STAGE(0, 0);
    STAGE(1, 1);
    asm volatile("s_waitcnt vmcnt(4)" ::: "memory");
    __builtin_amdgcn_s_barrier();

    int buf = 0, bs2 = 2;
    for (int t = 0; t < NT3; ++t) {
        if (t + 2 < NT3) STAGE(t + 2, bs2);  // 2-tile lead

        i32x4 a[4], b[4];
#pragma unroll
        for (int mi = 0; mi < 4; ++mi)
            a[mi] = *(const i32x4*)(As + buf * 8192 + (arowb + mi * 16) * BK3 + koffb);
#pragma unroll
        for (int n = 0; n < 4; ++n)
            b[n] = *(const i32x4*)(Bs + buf * 8192 + (browb + n * 16) * BK3 + koffb);

        __builtin_amdgcn_s_setprio(1);
#pragma unroll
        for (int mi = 0; mi < 4; ++mi)
#pragma unroll
            for (int n = 0; n < 4; ++n)
                acc[mi][n] = __builtin_amdgcn_mfma_i32_16x16x64_i8(a[mi], b[n], acc[mi][n], 0, 0, 0);
        __builtin_amdgcn_s_setprio(0);

        // ensure tile t+1 landed; keep tile t+2's 4 loads in flight
        if (t + 2 < NT3) {
            asm volatile("s_waitcnt vmcnt(4)" ::: "memory");
        } else if (t + 1 < NT3) {
            asm volatile("s_waitcnt vmcnt(0)" ::: "memory");
        }
        if (t + 1 < NT3) __builtin_amdgcn_s_barrier();

        buf = (buf == 2) ? 0 : buf + 1;
        bs2 = (bs2 == 2) ? 0 : bs2 + 1;
    }

    // epilogue: y = a_scale*w_scale[col]*(float)acc + bias[col]; tanh-GELU
    float asc = a_scale[0];
    long long row0 = mrow0 + wr * 64;
    int colb = ncol0 + wc * 64 + (lane & 15);
    int rsubE = (lane >> 4) * 4;
    bool fullTile = (mrow0 + 128 <= (long long)M);
    if (fullTile) {
#pragma unroll
        for (int n = 0; n < 4; ++n) {
            int col = colb + n * 16;
            float sc = asc * w_scale[col];
            float bz = bias[col];
#pragma unroll
            for (int m = 0; m < 4; ++m) {
                long long rb = row0 + m * 16 + rsubE;
#pragma unroll
                for (int rg = 0; rg < 4; ++rg) {
                    float y = (float)acc[m][n][rg] * sc + bz;
                    out[(rb + rg) * I_DIM + col] = gelu_tanh(y);
                }
            }
        }
    } else {
#pragma unroll
        for (int n = 0; n < 4; ++n) {
            int col = colb + n * 16;
            float sc = asc * w_scale[col];
            float bz = bias[col];
#pragma unroll
            for (int m = 0; m < 4; ++m) {
                long long rb = row0 + m * 16 + rsubE;
#pragma unroll
                for (int rg = 0; rg < 4; ++rg) {
                    long long rowi = rb + rg;
                    if (rowi < M) {
                        float y = (float)acc[m][n][rg] * sc + bz;
                        out[rowi * I_DIM + col] = gelu_tanh(y);
                    }
                }
            }
        }
    }
}

// ---- safety-net fallback (workspace too small): naive on-the-fly
__global__ void fallback_kernel(const float* __restrict__ x, const float* __restrict__ w,
                                const float* __restrict__ bias, const float* __restrict__ w_scale,
                                const float* __restrict__ w_zero, const float* __restrict__ a_scale,
                                const float* __restrict__ a_zero, float* __restrict__ out,
                                long long M) {
    long long gid = (long long)blockIdx.x * blockDim.x + threadIdx.x;
    if (gid >= M * I_DIM) return;
    int i = (int)(gid & (I_DIM - 1));
    long long row = gid >> 12;
    float as = a_scale[0], az = rintf(a_zero[0]);
    float wsc = w_scale[i], wz = rintf(w_zero[i]);
    const float* xr = x + row * K_DIM;
    const float* wrp = w + (long long)i * K_DIM;
    float accf = 0.0f;
    for (int k = 0; k < K_DIM; ++k)
        accf += fakeq_int(xr[k], as, az) * fakeq_int(wrp[k], wsc, wz);
    float y = accf * as * wsc + bias[i];
    out[gid] = 0.5f * y * (1.0f + erff(y * 0.70710678118654752f));
}

extern "C" void kernel_launch(void* const* d_in, const int* in_sizes, int n_in,
                              void* d_out, int out_size, void* d_ws, size_t ws_size,
                              hipStream_t stream) {
    const float* x       = (const float*)d_in[0];
    const float* w       = (const float*)d_in[1];
    const float* bias    = (const float*)d_in[2];
    const float* w_scale = (const float*)d_in[3];
    const float* w_zero  = (const float*)d_in[4];
    const float* a_scale = (const float*)d_in[5];
    const float* a_zero  = (const float*)d_in[6];
    float* out = (float*)d_out;

    long long n_x = in_sizes[0];  // M*K
    long long M = n_x / K_DIM;    // 12608
    size_t needA = ((size_t)n_x + 255) & ~(size_t)255;
    size_t needW = (size_t)I_DIM * K_DIM;

    if (ws_size >= needA + needW) {
        signed char* Aq = (signed char*)d_ws;
        signed char* Wq = (signed char*)((char*)d_ws + needA);

        long long blocksX = (n_x / 8 + 255) / 256;
        quant_x_kernel<<<(int)blocksX, 256, 0, stream>>>(x, Aq, a_scale, a_zero, n_x);

        long long ndw = (long long)I_DIM * K_DIM;
        long long blocksW = (ndw / 8 + 255) / 256;
        quant_w_kernel<<<(int)blocksW, 256, 0, stream>>>(w, Wq, w_scale, w_zero, ndw);

        int Mtiles = (int)((M + 127) / 128);  // 99
        int Ntiles = I_DIM / 128;             // 32
        gemm_gelu_kernel<<<Mtiles * Ntiles, 256, 0, stream>>>(Aq, Wq, bias, w_scale, a_scale,
                                                              out, (int)M, Ntiles);
    } else {
        long long total = M * I_DIM;
        long long blocks = (total + 255) / 256;
        fallback_kernel<<<(int)blocks, 256, 0, stream>>>(x, w, bias, w_scale, w_zero,
                                                         a_scale, a_zero, out, M);
    }
}

// Round 8
// 126.861 us; speedup vs baseline: 1.5006x; 1.0299x over previous
//
#include <hip/hip_runtime.h>
#include <hip/hip_bf16.h>

typedef __attribute__((ext_vector_type(4))) int i32x4;

#define K_DIM 1024
#define I_DIM 4096
#define BK3 64
#define NT3 (K_DIM / BK3)  // 16 K-tiles
// block tile 256(M) x 128(N); 4 waves (2x2), per-wave 128x64, i8 MFMA 16x16x64

__device__ __forceinline__ float fakeq_int(float x, float s, float zp) {
    // round(x/s)+zp clipped to [0,255], minus zp -> exact integer in [-128,127]
    float q = fminf(fmaxf(rintf(x / s) + zp, 0.0f), 255.0f);
    return q - zp;
}

// branch-free tanh-GELU: |err vs exact| <= ~3e-4
__device__ __forceinline__ float gelu_tanh(float y) {
    float y2 = y * y;
    float z = y * fmaf(0.0356774081f, y2, 0.7978845608f);
    return y / (1.0f + __expf(-2.0f * z));
}

// ---- quantize activations: fp32 -> int8 codes (q - zp), 8 elems/thread
__global__ void quant_x_kernel(const float* __restrict__ x, signed char* __restrict__ Aq,
                               const float* __restrict__ a_scale, const float* __restrict__ a_zero,
                               long long n) {
    long long i = ((long long)blockIdx.x * blockDim.x + threadIdx.x) * 8;
    if (i >= n) return;
    float s = a_scale[0];
    float zp = rintf(a_zero[0]);
    float4 v0 = *(const float4*)(x + i);
    float4 v1 = *(const float4*)(x + i + 4);
    int q0 = (int)fakeq_int(v0.x, s, zp), q1 = (int)fakeq_int(v0.y, s, zp);
    int q2 = (int)fakeq_int(v0.z, s, zp), q3 = (int)fakeq_int(v0.w, s, zp);
    int q4 = (int)fakeq_int(v1.x, s, zp), q5 = (int)fakeq_int(v1.y, s, zp);
    int q6 = (int)fakeq_int(v1.z, s, zp), q7 = (int)fakeq_int(v1.w, s, zp);
    int lo = (q0 & 255) | ((q1 & 255) << 8) | ((q2 & 255) << 16) | ((q3 & 255) << 24);
    int hi = (q4 & 255) | ((q5 & 255) << 8) | ((q6 & 255) << 16) | ((q7 & 255) << 24);
    *(int2*)(Aq + i) = make_int2(lo, hi);
}

// ---- quantize weights: per-row scale/zero, 8 elems/thread
__global__ void quant_w_kernel(const float* __restrict__ w, signed char* __restrict__ Wq,
                               const float* __restrict__ w_scale, const float* __restrict__ w_zero,
                               long long n) {
    long long i = ((long long)blockIdx.x * blockDim.x + threadIdx.x) * 8;
    if (i >= n) return;
    long long row = i >> 10;  // K = 1024
    float s = w_scale[row];
    float zp = rintf(w_zero[row]);
    float4 v0 = *(const float4*)(w + i);
    float4 v1 = *(const float4*)(w + i + 4);
    int q0 = (int)fakeq_int(v0.x, s, zp), q1 = (int)fakeq_int(v0.y, s, zp);
    int q2 = (int)fakeq_int(v0.z, s, zp), q3 = (int)fakeq_int(v0.w, s, zp);
    int q4 = (int)fakeq_int(v1.x, s, zp), q5 = (int)fakeq_int(v1.y, s, zp);
    int q6 = (int)fakeq_int(v1.z, s, zp), q7 = (int)fakeq_int(v1.w, s, zp);
    int lo = (q0 & 255) | ((q1 & 255) << 8) | ((q2 & 255) << 16) | ((q3 & 255) << 24);
    int hi = (q4 & 255) | ((q5 & 255) << 8) | ((q6 & 255) << 16) | ((q7 & 255) << 24);
    *(int2*)(Wq + i) = make_int2(lo, hi);
}

#define GLL(SRC, DST)                                                         \
    __builtin_amdgcn_global_load_lds(                                         \
        (const __attribute__((address_space(1))) void*)(SRC),                 \
        (__attribute__((address_space(3))) void*)(DST), 16, 0, 0)

// stage K-tile TT (A 256x64B = 4 chunks, B 128x64B = 2 chunks) into buffer BUF
#define STAGE(TT, BUF)                                            \
    do {                                                          \
        GLL(pA0 + (TT) * BK3, As + (BUF) * 16384 + dA);           \
        GLL(pA1 + (TT) * BK3, As + (BUF) * 16384 + 4096 + dA);    \
        GLL(pA2 + (TT) * BK3, As + (BUF) * 16384 + 8192 + dA);    \
        GLL(pA3 + (TT) * BK3, As + (BUF) * 16384 + 12288 + dA);   \
        GLL(pB0 + (TT) * BK3, Bs + (BUF) * 8192 + dA);            \
        GLL(pB1 + (TT) * BK3, Bs + (BUF) * 8192 + 4096 + dA);     \
    } while (0)

// ---- 256x128x64 i8 GEMM, per-wave 128x64, triple-buffered LDS (72KB, 2 blocks/CU),
//      rotation slot-swizzle (conflict-free, HW-verified r6/r7), counted vmcnt.
__global__ __launch_bounds__(256, 2) void gemm_gelu_kernel(
    const signed char* __restrict__ Aq,   // [M][K] int8 codes
    const signed char* __restrict__ Wq,   // [I][K]
    const float* __restrict__ bias,
    const float* __restrict__ w_scale,
    const float* __restrict__ a_scale,
    float* __restrict__ out,              // [M][I] fp32
    int M, int Ntiles) {
    __shared__ alignas(16) signed char As[3 * 256 * BK3];  // 48 KB
    __shared__ alignas(16) signed char Bs[3 * 128 * BK3];  // 24 KB

    // bijective XCD-aware swizzle (nwg % 8 == 0)
    int nwg = gridDim.x, bid = blockIdx.x;
    int xcd = bid & 7, lin = bid >> 3;
    int q8 = nwg >> 3, r8 = nwg & 7;
    int swz = (xcd < r8 ? xcd * (q8 + 1) : r8 * (q8 + 1) + (xcd - r8) * q8) + lin;
    int mt = swz / Ntiles, nt = swz % Ntiles;

    int tid = threadIdx.x;
    int wave = tid >> 6, lane = tid & 63;
    int wr = wave >> 1, wc = wave & 1;  // 2x2 waves, per-wave 128(M) x 64(N)

    long long mrow0 = (long long)mt * 256;
    int ncol0 = nt * 128;

    // staging: thread t covers row (chunk*64 + t>>2), LDS slot j = t&3 (16B slots).
    // rotation swizzle: LDS[row][j] holds source slot (j - (row>>1)) & 3
    int r0 = tid >> 2;                                  // 0..63
    int slotsrc = ((tid & 3) - ((tid >> 3) & 3)) & 3;
    long long mmax = (long long)M - 1;
    long long raA0 = mrow0 + r0;         if (raA0 > mmax) raA0 = mmax;
    long long raA1 = mrow0 + 64 + r0;    if (raA1 > mmax) raA1 = mmax;
    long long raA2 = mrow0 + 128 + r0;   if (raA2 > mmax) raA2 = mmax;
    long long raA3 = mrow0 + 192 + r0;   if (raA3 > mmax) raA3 = mmax;
    const signed char* pA0 = Aq + raA0 * K_DIM + slotsrc * 16;
    const signed char* pA1 = Aq + raA1 * K_DIM + slotsrc * 16;
    const signed char* pA2 = Aq + raA2 * K_DIM + slotsrc * 16;
    const signed char* pA3 = Aq + raA3 * K_DIM + slotsrc * 16;
    const signed char* pB0 = Wq + ((long long)ncol0 + r0) * K_DIM + slotsrc * 16;
    const signed char* pB1 = Wq + ((long long)ncol0 + 64 + r0) * K_DIM + slotsrc * 16;
    int dA = tid * 16;  // linear byte dest within each 4KB chunk region

    // ds_read: lane (r = lane&15, q = lane>>4) reads slot (q + (r>>1)) & 3
    // (row bases are multiples of 16, so (row>>1)&3 == ((lane&15)>>1)&3)
    int koffb = (((lane >> 4) + ((lane >> 1) & 3)) & 3) * 16;
    int arowb = wr * 128 + (lane & 15);
    int browb = wc * 64 + (lane & 15);

    i32x4 acc[8][4];
#pragma unroll
    for (int m = 0; m < 8; ++m)
#pragma unroll
        for (int n = 0; n < 4; ++n) acc[m][n] = (i32x4)0;

    // prologue: stage tiles 0,1; wait tile 0 (tile 1's 6 stay in flight)
    STAGE(0, 0);
    STAGE(1, 1);
    asm volatile("s_waitcnt vmcnt(6)" ::: "memory");
    __builtin_amdgcn_s_barrier();

    int buf = 0, bs2 = 2;
    for (int t = 0; t < NT3; ++t) {
        if (t + 2 < NT3) STAGE(t + 2, bs2);  // 2-tile lead

        i32x4 a[8], b[4];
#pragma unroll
        for (int mi = 0; mi < 8; ++mi)
            a[mi] = *(const i32x4*)(As + buf * 16384 + (arowb + mi * 16) * BK3 + koffb);
#pragma unroll
        for (int n = 0; n < 4; ++n)
            b[n] = *(const i32x4*)(Bs + buf * 8192 + (browb + n * 16) * BK3 + koffb);

        __builtin_amdgcn_s_setprio(1);
#pragma unroll
        for (int mi = 0; mi < 8; ++mi)
#pragma unroll
            for (int n = 0; n < 4; ++n)
                acc[mi][n] = __builtin_amdgcn_mfma_i32_16x16x64_i8(a[mi], b[n], acc[mi][n], 0, 0, 0);
        __builtin_amdgcn_s_setprio(0);

        // ensure tile t+1 landed; keep tile t+2's 6 loads in flight
        if (t + 2 < NT3) {
            asm volatile("s_waitcnt vmcnt(6)" ::: "memory");
        } else if (t + 1 < NT3) {
            asm volatile("s_waitcnt vmcnt(0)" ::: "memory");
        }
        if (t + 1 < NT3) __builtin_amdgcn_s_barrier();

        buf = (buf == 2) ? 0 : buf + 1;
        bs2 = (bs2 == 2) ? 0 : bs2 + 1;
    }

    // epilogue: y = a_scale*w_scale[col]*(float)acc + bias[col]; tanh-GELU
    float asc = a_scale[0];
    long long row0 = mrow0 + wr * 128;
    int colb = ncol0 + wc * 64 + (lane & 15);
    int rsubE = (lane >> 4) * 4;
    bool fullTile = (mrow0 + 256 <= (long long)M);
    if (fullTile) {
#pragma unroll
        for (int n = 0; n < 4; ++n) {
            int col = colb + n * 16;
            float sc = asc * w_scale[col];
            float bz = bias[col];
#pragma unroll
            for (int m = 0; m < 8; ++m) {
                long long rb = row0 + m * 16 + rsubE;
#pragma unroll
                for (int rg = 0; rg < 4; ++rg) {
                    float y = (float)acc[m][n][rg] * sc + bz;
                    out[(rb + rg) * I_DIM + col] = gelu_tanh(y);
                }
            }
        }
    } else {
#pragma unroll
        for (int n = 0; n < 4; ++n) {
            int col = colb + n * 16;
            float sc = asc * w_scale[col];
            float bz = bias[col];
#pragma unroll
            for (int m = 0; m < 8; ++m) {
                long long rb = row0 + m * 16 + rsubE;
#pragma unroll
                for (int rg = 0; rg < 4; ++rg) {
                    long long rowi = rb + rg;
                    if (rowi < M) {
                        float y = (float)acc[m][n][rg] * sc + bz;
                        out[rowi * I_DIM + col] = gelu_tanh(y);
                    }
                }
            }
        }
    }
}

// ---- safety-net fallback (workspace too small): naive on-the-fly
__global__ void fallback_kernel(const float* __restrict__ x, const float* __restrict__ w,
                                const float* __restrict__ bias, const float* __restrict__ w_scale,
                                const float* __restrict__ w_zero, const float* __restrict__ a_scale,
                                const float* __restrict__ a_zero, float* __restrict__ out,
                                long long M) {
    long long gid = (long long)blockIdx.x * blockDim.x + threadIdx.x;
    if (gid >= M * I_DIM) return;
    int i = (int)(gid & (I_DIM - 1));
    long long row = gid >> 12;
    float as = a_scale[0], az = rintf(a_zero[0]);
    float wsc = w_scale[i], wz = rintf(w_zero[i]);
    const float* xr = x + row * K_DIM;
    const float* wrp = w + (long long)i * K_DIM;
    float accf = 0.0f;
    for (int k = 0; k < K_DIM; ++k)
        accf += fakeq_int(xr[k], as, az) * fakeq_int(wrp[k], wsc, wz);
    float y = accf * as * wsc + bias[i];
    out[gid] = 0.5f * y * (1.0f + erff(y * 0.70710678118654752f));
}

extern "C" void kernel_launch(void* const* d_in, const int* in_sizes, int n_in,
                              void* d_out, int out_size, void* d_ws, size_t ws_size,
                              hipStream_t stream) {
    const float* x       = (const float*)d_in[0];
    const float* w       = (const float*)d_in[1];
    const float* bias    = (const float*)d_in[2];
    const float* w_scale = (const float*)d_in[3];
    const float* w_zero  = (const float*)d_in[4];
    const float* a_scale = (const float*)d_in[5];
    const float* a_zero  = (const float*)d_in[6];
    float* out = (float*)d_out;

    long long n_x = in_sizes[0];  // M*K
    long long M = n_x / K_DIM;    // 12608
    size_t needA = ((size_t)n_x + 255) & ~(size_t)255;
    size_t needW = (size_t)I_DIM * K_DIM;

    if (ws_size >= needA + needW) {
        signed char* Aq = (signed char*)d_ws;
        signed char* Wq = (signed char*)((char*)d_ws + needA);

        long long blocksX = (n_x / 8 + 255) / 256;
        quant_x_kernel<<<(int)blocksX, 256, 0, stream>>>(x, Aq, a_scale, a_zero, n_x);

        long long ndw = (long long)I_DIM * K_DIM;
        long long blocksW = (ndw / 8 + 255) / 256;
        quant_w_kernel<<<(int)blocksW, 256, 0, stream>>>(w, Wq, w_scale, w_zero, ndw);

        int Mtiles = (int)((M + 255) / 256);  // 50
        int Ntiles = I_DIM / 128;             // 32
        gemm_gelu_kernel<<<Mtiles * Ntiles, 256, 0, stream>>>(Aq, Wq, bias, w_scale, a_scale,
                                                              out, (int)M, Ntiles);
    } else {
        long long total = M * I_DIM;
        long long blocks = (total + 255) / 256;
        fallback_kernel<<<(int)blocks, 256, 0, stream>>>(x, w, bias, w_scale, w_zero,
                                                         a_scale, a_zero, out, M);
    }
}